// Round 4
// baseline (333.515 us; speedup 1.0000x reference)
//
#include <hip/hip_runtime.h>
#include <math.h>

// ---------------------------------------------------------------------------
// PointSampler / DevConv, CSR-gather with bucketed (write-coalesced) CSR build.
//   per layer l: y = h @ Cl.T  (f32) + y16 (bf16 copy, gather operand)
//                agg[i] = deg>0 ? (max_{j in N(i)} y16[j]) - y[i] : 0
//   head (fused into 3rd gather): out[i] = sigmoid( agg3[i] . v + b )
// max over bf16-rounded values; subtraction + GEMM chain stay f32.
// ---------------------------------------------------------------------------

#define WBITS 9
#define WNODES 512            // nodes per bucket
#define MAXNB 256             // max buckets (requires N <= 131072, src < 2^17)
#define CHUNK 8192            // edges per partA/hist block
#define STG_CAP 12288         // partB LDS staging entries (48 KB)

__device__ __forceinline__ unsigned bpack(float a, float b) {
    unsigned ua = __float_as_uint(a), ub = __float_as_uint(b);
    ua = ua + 0x7FFFu + ((ua >> 16) & 1u);          // RTNE to bf16
    ub = ub + 0x7FFFu + ((ub >> 16) & 1u);
    return (ua >> 16) | (ub & 0xFFFF0000u);
}

// block 0: C2 = Wp[1]@Wt[0];  block 1: C3 = Wp[2]@Wt[1];  block 2: v = Wout@Wt[2]
__global__ __launch_bounds__(256) void prep_k(
    const float* __restrict__ Wp, const float* __restrict__ Wt,
    const float* __restrict__ Wout,
    float* __restrict__ C2, float* __restrict__ C3, float* __restrict__ vout)
{
    __shared__ float A[4096];
    __shared__ float B[4096];
    int tid = threadIdx.x;
    int b = blockIdx.x;
    if (b < 2) {
        const float* Ap = Wp + (size_t)(b + 1) * 4096;
        const float* Bp = Wt + (size_t)b * 4096;
        for (int i = tid; i < 4096; i += 256) { A[i] = Ap[i]; B[i] = Bp[i]; }
        __syncthreads();
        float* C = b ? C3 : C2;
        for (int i = tid; i < 4096; i += 256) {
            int d = i >> 6, k = i & 63;
            float s = 0.f;
            #pragma unroll
            for (int m = 0; m < 64; ++m) s += A[d * 64 + m] * B[m * 64 + k];
            C[i] = s;
        }
    } else {
        for (int i = tid; i < 4096; i += 256) A[i] = Wt[2 * 4096 + i];
        if (tid < 64) B[tid] = Wout[tid];
        __syncthreads();
        if (tid < 64) {
            float s = 0.f;
            #pragma unroll
            for (int m = 0; m < 64; ++m) s += B[m] * A[m * 64 + tid];
            vout[tid] = s;
        }
    }
}

__global__ __launch_bounds__(256) void clear_int_k(int* __restrict__ p, int n)
{
    int i = blockIdx.x * 256 + threadIdx.x;
    if (i < n) p[i] = 0;
}

// per-chunk LDS histogram of dst buckets -> global bucket counts
__global__ __launch_bounds__(256) void bucket_hist_k(
    const int* __restrict__ eidx, int* __restrict__ bcnt, int E, int NB)
{
    __shared__ int h[MAXNB];
    int tid = threadIdx.x;
    for (int i = tid; i < NB; i += 256) h[i] = 0;
    __syncthreads();
    int start = blockIdx.x * CHUNK;
    int end = min(E, start + CHUNK);
    for (int e = start + tid; e < end; e += 256)
        atomicAdd(&h[eidx[E + e] >> WBITS], 1);
    __syncthreads();
    for (int i = tid; i < NB; i += 256)
        if (h[i]) atomicAdd(&bcnt[i], h[i]);
}

// 1-block scan of bucket counts -> bbase (exclusive), init gcur, row_ptr[N]=E
__global__ __launch_bounds__(256) void bucket_scan_k(
    const int* __restrict__ bcnt, int* __restrict__ bbase,
    int* __restrict__ gcur, int* __restrict__ row_ptr, int NB, int N, int E)
{
    __shared__ int sA[MAXNB], sB[MAXNB];
    int tid = threadIdx.x;
    int v0 = (tid < NB) ? bcnt[tid] : 0;
    sA[tid] = v0;
    __syncthreads();
    int* sp = sA; int* dp = sB;
    for (int off = 1; off < MAXNB; off <<= 1) {
        dp[tid] = sp[tid] + ((tid >= off) ? sp[tid - off] : 0);
        __syncthreads();
        int* t = sp; sp = dp; dp = t;
    }
    if (tid < NB) {
        int ex = sp[tid] - v0;
        bbase[tid] = ex;
        gcur[tid]  = ex;
    }
    if (tid == 0) {
        bbase[NB]  = E;
        row_ptr[N] = E;
    }
}

// partition edges into bucket-major order (packed src | dstLow<<17)
__global__ __launch_bounds__(256) void partA_k(
    const int* __restrict__ eidx, int* __restrict__ gcur,
    int* __restrict__ B1, int E, int NB)
{
    __shared__ int hist[MAXNB];
    __shared__ int lofs[MAXNB];
    __shared__ int lcur[MAXNB];
    __shared__ int gofs[MAXNB];
    __shared__ int sA[MAXNB], sB[MAXNB];
    __shared__ int stg_val[CHUNK];
    __shared__ int stg_pos[CHUNK];
    int tid = threadIdx.x;
    int start = blockIdx.x * CHUNK;
    int cnt = min(E - start, CHUNK);
    if (cnt <= 0) return;

    for (int i = tid; i < NB; i += 256) hist[i] = 0;
    __syncthreads();

    int es[CHUNK / 256], ed[CHUNK / 256];
    #pragma unroll
    for (int i = 0; i < CHUNK / 256; ++i) {
        int li = i * 256 + tid;
        if (li < cnt) {
            es[i] = eidx[start + li];
            ed[i] = eidx[E + start + li];
            atomicAdd(&hist[ed[i] >> WBITS], 1);
        }
    }
    __syncthreads();
    sA[tid] = (tid < NB) ? hist[tid] : 0;
    __syncthreads();
    int* sp = sA; int* dp = sB;
    for (int off = 1; off < MAXNB; off <<= 1) {
        dp[tid] = sp[tid] + ((tid >= off) ? sp[tid - off] : 0);
        __syncthreads();
        int* t = sp; sp = dp; dp = t;
    }
    if (tid < NB) {
        int c  = hist[tid];
        int ex = sp[tid] - c;
        lofs[tid] = ex;
        lcur[tid] = ex;
        gofs[tid] = c ? atomicAdd(&gcur[tid], c) : 0;
    }
    __syncthreads();
    #pragma unroll
    for (int i = 0; i < CHUNK / 256; ++i) {
        int li = i * 256 + tid;
        if (li < cnt) {
            int b = ed[i] >> WBITS;
            int p = atomicAdd(&lcur[b], 1);
            stg_val[p] = es[i] | ((ed[i] & (WNODES - 1)) << 17);
            stg_pos[p] = gofs[b] + (p - lofs[b]);
        }
    }
    __syncthreads();
    for (int i = tid; i < cnt; i += 256)
        B1[stg_pos[i]] = stg_val[i];
}

// per-bucket: degree count -> scan -> row_ptr; LDS-staged coalesced col scatter
__global__ __launch_bounds__(256) void partB_k(
    const int* __restrict__ B1, const int* __restrict__ bbase,
    int* __restrict__ row_ptr, int* __restrict__ col, int N, int NB)
{
    __shared__ int cnt[WNODES];
    __shared__ int lcur[WNODES];
    __shared__ int sA[WNODES], sB[WNODES];
    __shared__ int stg[STG_CAP];
    int b   = blockIdx.x;
    int tid = threadIdx.x;
    int gb0 = bbase[b], gb1 = bbase[b + 1];
    int m   = gb1 - gb0;
    int nb0 = b << WBITS;

    for (int i = tid; i < WNODES; i += 256) cnt[i] = 0;
    __syncthreads();
    for (int i = tid; i < m; i += 256)
        atomicAdd(&cnt[B1[gb0 + i] >> 17], 1);
    __syncthreads();
    for (int i = tid; i < WNODES; i += 256) sA[i] = cnt[i];
    __syncthreads();
    int* sp = sA; int* dp = sB;
    for (int off = 1; off < WNODES; off <<= 1) {
        for (int i = tid; i < WNODES; i += 256)
            dp[i] = sp[i] + ((i >= off) ? sp[i - off] : 0);
        __syncthreads();
        int* t = sp; sp = dp; dp = t;
    }
    for (int i = tid; i < WNODES; i += 256) {
        int ex = sp[i] - cnt[i];
        lcur[i] = ex;
        int node = nb0 + i;
        if (node < N) row_ptr[node] = gb0 + ex;
    }
    __syncthreads();
    if (m <= STG_CAP) {
        for (int i = tid; i < m; i += 256) {
            int v = B1[gb0 + i];
            int p = atomicAdd(&lcur[v >> 17], 1);
            stg[p] = v & 0x1FFFF;
        }
        __syncthreads();
        for (int i = tid; i < m; i += 256)
            col[gb0 + i] = stg[i];
    } else {               // adversarial-degree fallback (correct, uncoalesced)
        for (int i = tid; i < m; i += 256) {
            int v = B1[gb0 + i];
            int p = atomicAdd(&lcur[v >> 17], 1);
            col[gb0 + p] = v & 0x1FFFF;
        }
    }
}

// ---------------- per-layer kernels ----------------

// y[r][:] = in_row(r) @ C.T (f32) + bf16 copy y16; one thread per row.
__global__ __launch_bounds__(256) void gemm64_k(
    const float* __restrict__ in,
    const float* __restrict__ C,      // [64][64] row-major, C[d][k]
    float* __restrict__ out, unsigned* __restrict__ out16, int n)
{
    __shared__ float sCT[64 * 68];    // sCT[k*68 + d]
    int tid = threadIdx.x;
    for (int i = tid; i < 4096; i += 256) {
        int d = i >> 6, k = i & 63;
        sCT[k * 68 + d] = C[i];
    }
    __syncthreads();
    int r = blockIdx.x * 256 + tid;
    if (r >= n) return;

    float xr[64];
    const float4* xp = (const float4*)(in + (size_t)r * 64);
    #pragma unroll
    for (int k4 = 0; k4 < 16; ++k4) {
        float4 v = xp[k4];
        xr[k4 * 4 + 0] = v.x; xr[k4 * 4 + 1] = v.y;
        xr[k4 * 4 + 2] = v.z; xr[k4 * 4 + 3] = v.w;
    }

    float4* op  = (float4*)(out + (size_t)r * 64);
    uint2*  o16 = (uint2*)(out16 + (size_t)r * 32);
    for (int dg = 0; dg < 16; ++dg) {
        float a0 = 0.f, a1 = 0.f, a2 = 0.f, a3 = 0.f;
        #pragma unroll
        for (int k = 0; k < 64; ++k) {
            float4 c = *(const float4*)&sCT[k * 68 + dg * 4];
            a0 += xr[k] * c.x;
            a1 += xr[k] * c.y;
            a2 += xr[k] * c.z;
            a3 += xr[k] * c.w;
        }
        float4 o; o.x = a0; o.y = a1; o.z = a2; o.w = a3;
        op[dg] = o;
        uint2 p; p.x = bpack(a0, a1); p.y = bpack(a2, a3);
        o16[dg] = p;
    }
}

// one wave per node. bf16 rows (128B): lanes 0-31 process even edges, 32-63 odd
// edges; each lane holds components {2*(lane&31), +1}. Halves merged by
// shfl_xor(32). Subtraction uses exact f32 y_i. FINAL fuses the linear head.
template<bool FINAL>
__global__ __launch_bounds__(256) void gather_max_k(
    const int* __restrict__ row_ptr, const int* __restrict__ col,
    const unsigned* __restrict__ y16, const float* __restrict__ y,
    float* __restrict__ agg,
    const float* __restrict__ v, const float* __restrict__ bptr,
    float* __restrict__ out, int n)
{
    int gid  = blockIdx.x * 256 + threadIdx.x;
    int node = gid >> 6;
    int lane = threadIdx.x & 63;
    int h    = lane >> 5;           // half-wave: which edge of the pair
    int l5   = lane & 31;           // component pair index
    if (node >= n) return;
    int beg = row_ptr[node], end = row_ptr[node + 1];

    float aLo = -INFINITY, aHi = -INFINITY;
    float bLo = -INFINITY, bHi = -INFINITY;
    for (int base = beg; base < end; base += 64) {
        int idx = base + lane;
        int myc = (idx < end) ? col[idx] : 0;
        int cnt = min(64, end - base);
        int k = 0;
        for (; k + 4 <= cnt; k += 4) {
            int jA = __shfl(myc, k + h);
            int jB = __shfl(myc, k + 2 + h);
            unsigned vA = y16[(size_t)jA * 32 + l5];
            unsigned vB = y16[(size_t)jB * 32 + l5];
            aLo = fmaxf(aLo, __uint_as_float(vA << 16));
            aHi = fmaxf(aHi, __uint_as_float(vA & 0xFFFF0000u));
            bLo = fmaxf(bLo, __uint_as_float(vB << 16));
            bHi = fmaxf(bHi, __uint_as_float(vB & 0xFFFF0000u));
        }
        for (; k < cnt; k += 2) {
            int j = __shfl(myc, k + h);
            unsigned vA = y16[(size_t)j * 32 + l5];
            if (k + h >= cnt) vA = 0xFF80FF80u;     // bf16 -inf pair
            aLo = fmaxf(aLo, __uint_as_float(vA << 16));
            aHi = fmaxf(aHi, __uint_as_float(vA & 0xFFFF0000u));
        }
    }
    aLo = fmaxf(aLo, bLo);
    aHi = fmaxf(aHi, bHi);
    aLo = fmaxf(aLo, __shfl_xor(aLo, 32));
    aHi = fmaxf(aHi, __shfl_xor(aHi, 32));

    if (!FINAL) {
        if (h == 0) {
            float2 yi = ((const float2*)y)[(size_t)node * 32 + l5];
            float2 o;
            o.x = (end > beg) ? (aLo - yi.x) : 0.f;
            o.y = (end > beg) ? (aHi - yi.y) : 0.f;
            ((float2*)agg)[(size_t)node * 32 + l5] = o;
        }
    } else {
        float t = 0.f;
        if (h == 0) {
            float2 yi = ((const float2*)y)[(size_t)node * 32 + l5];
            float2 vp = ((const float2*)v)[l5];
            float g0 = (end > beg) ? (aLo - yi.x) : 0.f;
            float g1 = (end > beg) ? (aHi - yi.y) : 0.f;
            t = g0 * vp.x + g1 * vp.y;
        }
        #pragma unroll
        for (int off = 16; off >= 1; off >>= 1)
            t += __shfl_xor(t, off);
        if (lane == 0)
            out[node] = 1.f / (1.f + __expf(-(t + bptr[0])));
    }
}

extern "C" void kernel_launch(void* const* d_in, const int* in_sizes, int n_in,
                              void* d_out, int out_size, void* d_ws, size_t ws_size,
                              hipStream_t stream)
{
    const float* x     = (const float*)d_in[0];
    const int*   edges = (const int*)d_in[1];   // int32 view, [2][E]
    const float* Wp    = (const float*)d_in[2];
    const float* Wt    = (const float*)d_in[3];
    const float* Wout  = (const float*)d_in[4];
    const float* bout  = (const float*)d_in[5];
    const int N = in_sizes[0] / 64;             // 100000
    const int E = in_sizes[1] / 2;              // 1600000
    const int NB = (N + WNODES - 1) >> WBITS;   // 196
    float* out = (float*)d_out;

    char* ws = (char*)d_ws;
    float* y    = (float*)ws; ws += (size_t)N * 64 * 4;
    float* agg  = (float*)ws; ws += (size_t)N * 64 * 4;
    int*   B1   = (int*)agg;                    // alias: B1 dead before agg live
    unsigned* y16 = (unsigned*)ws; ws += (size_t)N * 32 * 4;
    int* col     = (int*)ws; ws += (size_t)E * 4;
    int* row_ptr = (int*)ws; ws += (size_t)(N + 4) * 4;
    int* bcnt    = (int*)ws; ws += MAXNB * 4;
    int* bbase   = (int*)ws; ws += (MAXNB + 4) * 4;
    int* gcur    = (int*)ws; ws += MAXNB * 4;
    float* C2 = (float*)ws; ws += 4096 * 4;
    float* C3 = (float*)ws; ws += 4096 * 4;
    float* vv = (float*)ws; ws += 64 * 4;

    const int nodeBlocks   = (N + 255) / 256;
    const int chunkBlocks  = (E + CHUNK - 1) / CHUNK;
    const int gatherBlocks = (N * 64 + 255) / 256;

    prep_k<<<3, 256, 0, stream>>>(Wp, Wt, Wout, C2, C3, vv);

    // CSR build (bucketed, write-coalesced)
    clear_int_k<<<1, 256, 0, stream>>>(bcnt, NB);
    bucket_hist_k<<<chunkBlocks, 256, 0, stream>>>(edges, bcnt, E, NB);
    bucket_scan_k<<<1, 256, 0, stream>>>(bcnt, bbase, gcur, row_ptr, NB, N, E);
    partA_k<<<chunkBlocks, 256, 0, stream>>>(edges, gcur, B1, E, NB);
    partB_k<<<NB, 256, 0, stream>>>(B1, bbase, row_ptr, col, N, NB);

    // layer 1
    gemm64_k<<<nodeBlocks, 256, 0, stream>>>(x, Wp, y, y16, N);
    gather_max_k<false><<<gatherBlocks, 256, 0, stream>>>(row_ptr, col, y16, y, agg,
                                                          nullptr, nullptr, nullptr, N);
    // layer 2
    gemm64_k<<<nodeBlocks, 256, 0, stream>>>(agg, C2, y, y16, N);
    gather_max_k<false><<<gatherBlocks, 256, 0, stream>>>(row_ptr, col, y16, y, agg,
                                                          nullptr, nullptr, nullptr, N);
    // layer 3
    gemm64_k<<<nodeBlocks, 256, 0, stream>>>(agg, C3, y, y16, N);
    gather_max_k<true><<<gatherBlocks, 256, 0, stream>>>(row_ptr, col, y16, y, nullptr,
                                                         vv, bout, out, N);
}